// Round 8
// baseline (981.595 us; speedup 1.0000x reference)
//
#include <hip/hip_runtime.h>
#include <math.h>

#define NUM_LAYER 6

typedef __attribute__((ext_vector_type(8))) short short8;
typedef __attribute__((ext_vector_type(4))) float f32x4;
typedef unsigned short u16;

// Exact 3-way bf16 truncation split: x == h + m + l bit-exactly (8+8+8 bits).
__device__ __forceinline__ void split3(float x, u16& h, u16& m, u16& l) {
  unsigned ux = __float_as_uint(x);
  h = (u16)(ux >> 16);
  float r1 = x - __uint_as_float(ux & 0xFFFF0000u);
  unsigned u1 = __float_as_uint(r1);
  m = (u16)(u1 >> 16);
  float r2 = r1 - __uint_as_float(u1 & 0xFFFF0000u);
  l = (u16)(__float_as_uint(r2) >> 16);
}

// ---------------- Pass A: Q = Wq*vf + bq ; K = Wk*ef + bk ----------------
__global__ __launch_bounds__(256) void qk_gemm_split(
    const float* __restrict__ Wq, const float* __restrict__ bq,
    const float* __restrict__ vf,
    const float* __restrict__ Wk, const float* __restrict__ bk,
    const float* __restrict__ ef,
    u16* __restrict__ Qh, u16* __restrict__ Qm, u16* __restrict__ Ql,
    u16* __restrict__ Kh, u16* __restrict__ Km, u16* __restrict__ Kl,
    int C, int N, int bs) {
  int which = (int)blockIdx.y >= bs;
  int b = (int)blockIdx.y - (which ? bs : 0);
  const float* Wm = which ? Wk : Wq;
  const float* bias = which ? bk : bq;
  const float* X = (which ? ef : vf) + (size_t)b * C * N;
  u16* Ph = which ? Kh : Qh;
  u16* Pm = which ? Km : Qm;
  u16* Pl = which ? Kl : Ql;
  int n0 = blockIdx.x * 128;
  __shared__ float As[8][128];
  __shared__ float Xs[8][128];
  int t = threadIdx.x;
  int tx = t & 15, ty = t >> 4;
  int ao = t >> 1, ac = (t & 1) * 4;
  int lk = t >> 5, lj = (t & 31) * 4;
  float acc[8][8] = {};
  for (int c0 = 0; c0 < C; c0 += 8) {
    __syncthreads();
    float4 wv = *(const float4*)&Wm[(size_t)ao * C + c0 + ac];
    As[ac + 0][ao] = wv.x; As[ac + 1][ao] = wv.y;
    As[ac + 2][ao] = wv.z; As[ac + 3][ao] = wv.w;
    *(float4*)&Xs[lk][lj] = *(const float4*)&X[(size_t)(c0 + lk) * N + n0 + lj];
    __syncthreads();
#pragma unroll
    for (int kk = 0; kk < 8; ++kk) {
      float a[8], bb[8];
      *(float4*)&a[0]  = *(const float4*)&As[kk][ty * 4];
      *(float4*)&a[4]  = *(const float4*)&As[kk][64 + ty * 4];
      *(float4*)&bb[0] = *(const float4*)&Xs[kk][tx * 4];
      *(float4*)&bb[4] = *(const float4*)&Xs[kk][64 + tx * 4];
#pragma unroll
      for (int i = 0; i < 8; ++i)
#pragma unroll
        for (int j = 0; j < 8; ++j)
          acc[i][j] = fmaf(a[i], bb[j], acc[i][j]);
    }
  }
  float bv[8];
#pragma unroll
  for (int i = 0; i < 8; ++i) bv[i] = bias[(i >> 2) * 64 + ty * 4 + (i & 3)];
#pragma unroll
  for (int j = 0; j < 8; ++j) {
    int n = n0 + tx * 4 + (j & 3) + (j >> 2) * 64;
    size_t nb = ((size_t)b * N + n) * C;
#pragma unroll
    for (int g = 0; g < 2; ++g) {
      int r0 = g * 64 + ty * 4;
      ushort4 hv, mv, lv;
      split3(acc[g * 4 + 0][j] + bv[g * 4 + 0], hv.x, mv.x, lv.x);
      split3(acc[g * 4 + 1][j] + bv[g * 4 + 1], hv.y, mv.y, lv.y);
      split3(acc[g * 4 + 2][j] + bv[g * 4 + 2], hv.z, mv.z, lv.z);
      split3(acc[g * 4 + 3][j] + bv[g * 4 + 3], hv.w, mv.w, lv.w);
      *(ushort4*)&Ph[nb + r0] = hv;
      *(ushort4*)&Pm[nb + r0] = mv;
      *(ushort4*)&Pl[nb + r0] = lv;
    }
  }
}

// ---------------- Pass B: score via MFMA bf16 3-split, reg-prefetch pipe ----
__global__ __launch_bounds__(256) void att_mfma(
    const u16* __restrict__ Qh, const u16* __restrict__ Qm,
    const u16* __restrict__ Ql, const u16* __restrict__ Kh,
    const u16* __restrict__ Km, const u16* __restrict__ Kl,
    const float* __restrict__ H0, float* __restrict__ score,
    int C, int N, float rsdh) {
  int b = blockIdx.z;
  int o0 = blockIdx.y * 128, i0 = blockIdx.x * 128;
  __shared__ u16 sm[6][128][40];   // [Qh,Qm,Ql,Kh,Km,Kl][row][kpad]
  __shared__ float et[4][16][68];  // per-wave epilogue transpose tile
  int t = threadIdx.x;
  int wave = t >> 6, lane = t & 63, quad = lane >> 4, lr = lane & 15;
  int wo = wave >> 1, wi = wave & 1;
  f32x4 acc[4][4];
#pragma unroll
  for (int mi = 0; mi < 4; ++mi)
#pragma unroll
    for (int ni = 0; ni < 4; ++ni) acc[mi][ni] = (f32x4){0.f, 0.f, 0.f, 0.f};

  int ro = t >> 1, ch = (t & 1) * 16;
  size_t qbase = ((size_t)b * N + o0 + ro) * C + ch;
  size_t kbase = ((size_t)b * N + i0 + ro) * C + ch;
  const u16* gq[3] = {Qh, Qm, Ql};
  const u16* gk[3] = {Kh, Km, Kl};

  // register prefetch buffer: chunk c+1 loads overlap chunk c MFMA
  uint4 pre[12];
#pragma unroll
  for (int a = 0; a < 3; ++a) {
    pre[a * 4 + 0] = ((const uint4*)(gq[a] + qbase))[0];
    pre[a * 4 + 1] = ((const uint4*)(gq[a] + qbase))[1];
    pre[a * 4 + 2] = ((const uint4*)(gk[a] + kbase))[0];
    pre[a * 4 + 3] = ((const uint4*)(gk[a] + kbase))[1];
  }

  for (int c0 = 0; c0 < C; c0 += 32) {
    __syncthreads();  // sm free (previous compute done)
#pragma unroll
    for (int a = 0; a < 3; ++a) {
      *(uint4*)&sm[a][ro][ch]         = pre[a * 4 + 0];
      *(uint4*)&sm[a][ro][ch + 8]     = pre[a * 4 + 1];
      *(uint4*)&sm[3 + a][ro][ch]     = pre[a * 4 + 2];
      *(uint4*)&sm[3 + a][ro][ch + 8] = pre[a * 4 + 3];
    }
    __syncthreads();
    if (c0 + 32 < C) {
      int cn = c0 + 32;
#pragma unroll
      for (int a = 0; a < 3; ++a) {
        pre[a * 4 + 0] = ((const uint4*)(gq[a] + qbase + cn))[0];
        pre[a * 4 + 1] = ((const uint4*)(gq[a] + qbase + cn))[1];
        pre[a * 4 + 2] = ((const uint4*)(gk[a] + kbase + cn))[0];
        pre[a * 4 + 3] = ((const uint4*)(gk[a] + kbase + cn))[1];
      }
    }
    short8 bh[4], bm[4], bl[4];
#pragma unroll
    for (int ni = 0; ni < 4; ++ni) {
      int row = wi * 64 + ni * 16 + lr;
      bh[ni] = *(const short8*)&sm[3][row][quad * 8];
      bm[ni] = *(const short8*)&sm[4][row][quad * 8];
      bl[ni] = *(const short8*)&sm[5][row][quad * 8];
    }
#pragma unroll
    for (int mi = 0; mi < 4; ++mi) {
      int row = wo * 64 + mi * 16 + lr;
      short8 ah = *(const short8*)&sm[0][row][quad * 8];
      short8 am = *(const short8*)&sm[1][row][quad * 8];
      short8 al = *(const short8*)&sm[2][row][quad * 8];
#pragma unroll
      for (int ni = 0; ni < 4; ++ni) {
        f32x4 c = acc[mi][ni];
        c = __builtin_amdgcn_mfma_f32_16x16x32_bf16(ah, bl[ni], c, 0, 0, 0);
        c = __builtin_amdgcn_mfma_f32_16x16x32_bf16(al, bh[ni], c, 0, 0, 0);
        c = __builtin_amdgcn_mfma_f32_16x16x32_bf16(am, bm[ni], c, 0, 0, 0);
        c = __builtin_amdgcn_mfma_f32_16x16x32_bf16(ah, bm[ni], c, 0, 0, 0);
        c = __builtin_amdgcn_mfma_f32_16x16x32_bf16(am, bh[ni], c, 0, 0, 0);
        c = __builtin_amdgcn_mfma_f32_16x16x32_bf16(ah, bh[ni], c, 0, 0, 0);
        acc[mi][ni] = c;
      }
    }
  }
  // epilogue: et is wave-private -> no block barriers needed (intra-wave DS
  // ordering is program order; compiler inserts lgkmcnt waits).
  const float* Hb = H0 + (size_t)b * N * N;
  float* Sb = score + (size_t)b * N * N;
  int rr = lane >> 2, seg = lane & 3;
#pragma unroll
  for (int mi = 0; mi < 4; ++mi) {
#pragma unroll
    for (int ni = 0; ni < 4; ++ni)
#pragma unroll
      for (int r = 0; r < 4; ++r)
        et[wave][quad * 4 + r][ni * 16 + lr] = acc[mi][ni][r];
    int o = o0 + wo * 64 + mi * 16 + rr;
    const float* hr = Hb + (size_t)o * N + i0 + wi * 64;
    float* sr = Sb + (size_t)o * N + i0 + wi * 64;
#pragma unroll
    for (int j = 0; j < 4; ++j) {
      int col = j * 16 + seg * 4;
      float4 c = *(const float4*)&et[wave][rr][col];
      float4 h = *(const float4*)&hr[col];
      float4 oV;
      oV.x = (h.x > 0.f) ? 1.f / (1.f + __expf(-c.x * rsdh)) : 0.f;
      oV.y = (h.y > 0.f) ? 1.f / (1.f + __expf(-c.y * rsdh)) : 0.f;
      oV.z = (h.z > 0.f) ? 1.f / (1.f + __expf(-c.z * rsdh)) : 0.f;
      oV.w = (h.w > 0.f) ? 1.f / (1.f + __expf(-c.w * rsdh)) : 0.f;
      *(float4*)&sr[col] = oV;
    }
  }
}

// ---- Pass C (fused): per-row exact k-th largest + select from registers.
// H0 binary => H = (W>0) ? 1 : 0 (bit-exact); no H0 read needed.
// grid (N/8, bs); block 512 = 8 waves; wave w owns row strip*8+w.
template <int V4>
__global__ __launch_bounds__(512) void topk_select(
    float* __restrict__ scoreW, float* __restrict__ Hout,
    float* __restrict__ degV, float* __restrict__ PE, float* __restrict__ PW,
    const int* __restrict__ itp, int N) {
  int b = blockIdx.y;
  int strip = blockIdx.x;
  int t = threadIdx.x;
  int wave = t >> 6, lane = t & 63;
  int row = strip * 8 + wave;
  size_t rowoff = ((size_t)b * N + row) * N;
  extern __shared__ float cols[];  // [2][N]: colE, colW
  float* colE = cols;
  float* colW = cols + N;
  for (int i = t; i < 2 * N; i += 512) cols[i] = 0.f;

  // phase 1: load row into registers, exact k-th largest (bitwise search)
  float4 v4[V4];
#pragma unroll
  for (int q = 0; q < V4; ++q)
    v4[q] = *(const float4*)(scoreW + rowoff + 4 * lane + (q << 8));
  int itv = *itp;
  int k = (int)floor((double)N * 0.1 * (double)(NUM_LAYER - 1 - itv) + 0.5);
  unsigned lo = 0u, hi = 0x3F800000u;  // scores in [0, 1]
  while (lo < hi) {
    unsigned mid = lo + ((hi - lo + 1u) >> 1);
    float thr = __uint_as_float(mid);
    int c = 0;
#pragma unroll
    for (int q = 0; q < V4; ++q) {
      c += (v4[q].x >= thr) ? 1 : 0;
      c += (v4[q].y >= thr) ? 1 : 0;
      c += (v4[q].z >= thr) ? 1 : 0;
      c += (v4[q].w >= thr) ? 1 : 0;
    }
#pragma unroll
    for (int off = 1; off < 64; off <<= 1) c += __shfl_xor(c, off);
    if (c >= k) lo = mid; else hi = mid - 1u;
  }
  float am = __uint_as_float(lo);  // uniform across wave
  __syncthreads();                 // cols[] zeroed

  // phase 2: select from registers, write W/H, accumulate partials
  float rs = 0.f;
#pragma unroll
  for (int q = 0; q < V4; ++q) {
    int c0 = 4 * lane + (q << 8);
    float4 s = v4[q];
    float4 w, h;
    w.x = (s.x >= am) ? s.x : 0.f; h.x = (w.x > 0.f) ? 1.f : 0.f;
    w.y = (s.y >= am) ? s.y : 0.f; h.y = (w.y > 0.f) ? 1.f : 0.f;
    w.z = (s.z >= am) ? s.z : 0.f; h.z = (w.z > 0.f) ? 1.f : 0.f;
    w.w = (s.w >= am) ? s.w : 0.f; h.w = (w.w > 0.f) ? 1.f : 0.f;
    *(float4*)(scoreW + rowoff + c0) = w;
    *(float4*)(Hout + rowoff + c0) = h;
    rs += h.x + h.y + h.z + h.w;
    if (h.x != 0.f) { atomicAdd(&colE[c0 + 0], 1.f); atomicAdd(&colW[c0 + 0], w.x); }
    if (h.y != 0.f) { atomicAdd(&colE[c0 + 1], 1.f); atomicAdd(&colW[c0 + 1], w.y); }
    if (h.z != 0.f) { atomicAdd(&colE[c0 + 2], 1.f); atomicAdd(&colW[c0 + 2], w.z); }
    if (h.w != 0.f) { atomicAdd(&colE[c0 + 3], 1.f); atomicAdd(&colW[c0 + 3], w.w); }
  }
#pragma unroll
  for (int off = 32; off; off >>= 1) rs += __shfl_down(rs, off);
  if (lane == 0) degV[b * N + row] = rs;
  __syncthreads();
  int S = N >> 3;
  size_t pbase = ((size_t)b * S + strip) * N;
  for (int c = 4 * t; c < N; c += 2048) {
    *(float4*)(PE + pbase + c) = *(const float4*)&colE[c];
    *(float4*)(PW + pbase + c) = *(const float4*)&colW[c];
  }
}

// ---------------- Pass D: reduce column partials -> degE, We ----------------
__global__ __launch_bounds__(256) void col_reduce(
    const float* __restrict__ PE, const float* __restrict__ PW,
    float* __restrict__ degE, float* __restrict__ We, int N, int S) {
  int b = blockIdx.y;
  int col = blockIdx.x * 256 + threadIdx.x;
  float se0 = 0.f, se1 = 0.f, sw0 = 0.f, sw1 = 0.f;
  for (int s = 0; s < S; s += 4) {
    size_t o0 = ((size_t)b * S + s) * N + col;
    se0 += PE[o0];           sw0 += PW[o0];
    se1 += PE[o0 + N];       sw1 += PW[o0 + N];
    se0 += PE[o0 + 2 * (size_t)N]; sw0 += PW[o0 + 2 * (size_t)N];
    se1 += PE[o0 + 3 * (size_t)N]; sw1 += PW[o0 + 3 * (size_t)N];
  }
  degE[b * N + col] = se0 + se1;
  We[b * N + col] = sw0 + sw1;
}

// ------- Pass E: streaming fill of De and Dv (zeros + 1/deg diagonal) -------
__global__ __launch_bounds__(256) void dedv_fill(
    float* __restrict__ De, float* __restrict__ Dv,
    const float* __restrict__ degE, const float* __restrict__ degV, int N) {
  int arr = blockIdx.z;
  int b = blockIdx.y;
  int r0 = blockIdx.x * 8;
  float* out = (arr ? Dv : De) + (size_t)b * N * N;
  const float* deg = (arr ? degV : degE) + b * N;
  int t = threadIdx.x;
#pragma unroll
  for (int r = r0; r < r0 + 8; ++r) {
    float d = deg[r];
    float inv = (d != 0.f) ? 1.f / d : 0.f;
    size_t rowoff = (size_t)r * N;
    for (int c4 = t * 4; c4 < N; c4 += 1024) {
      float4 v = {0.f, 0.f, 0.f, 0.f};
      unsigned dd = (unsigned)(r - c4);
      if (dd < 4u) ((float*)&v)[dd] = inv;
      *(float4*)&out[rowoff + c4] = v;
    }
  }
}

// ---------------- Pass F: W_edge normalize ----------------
__global__ __launch_bounds__(256) void wedge_norm(
    const float* __restrict__ We, float* __restrict__ out, int N) {
  int b = blockIdx.x;
  int t = threadIdx.x;
  const float* w = We + (size_t)b * N;
  float ss = 0.f;
  for (int i = t; i < N; i += 256) { float x = w[i]; ss += x * x; }
  for (int off = 32; off; off >>= 1) ss += __shfl_down(ss, off);
  __shared__ float p[4];
  if ((t & 63) == 0) p[t >> 6] = ss;
  __syncthreads();
  float tot = p[0] + p[1] + p[2] + p[3];
  float nrm = fmaxf(sqrtf(tot), 1e-12f);
  for (int i = t; i < N; i += 256) out[(size_t)b * N + i] = w[i] / nrm;
}

extern "C" void kernel_launch(void* const* d_in, const int* in_sizes, int n_in,
                              void* d_out, int out_size, void* d_ws, size_t ws_size,
                              hipStream_t stream) {
  const float* H0 = (const float*)d_in[0];
  const float* vf = (const float*)d_in[1];
  const float* ef = (const float*)d_in[2];
  const float* Wq = (const float*)d_in[3];
  const float* bq = (const float*)d_in[4];
  const float* Wk = (const float*)d_in[5];
  const float* bk = (const float*)d_in[6];
  const int* itp  = (const int*)d_in[7];

  int C = (int)(sqrt((double)in_sizes[3]) + 0.5);          // 128
  long long ratio = (long long)in_sizes[0] / in_sizes[1];  // N/C
  int N = (int)(C * ratio);                                // 2048
  int bs = (int)(in_sizes[1] / ((long long)C * N));        // 8
  size_t bNN = (size_t)bs * N * N;
  size_t bNC = (size_t)bs * N * C;
  int S = N >> 3;                                          // 8-row strips
  size_t pElems = (size_t)bs * S * N;

  float* outH  = (float*)d_out;
  float* outW  = outH + bNN;
  float* outDe = outW + bNN;
  float* outDv = outDe + bNN;
  float* outWe = outDv + bNN;

  size_t bsN = (size_t)bs * N;
  float* degE = (float*)d_ws;
  float* degV = degE + bsN;
  float* We   = degV + bsN;
  u16* splits;   // 6 arrays of bNC u16 each
  float* PE;
  float* PW;
  size_t need = 3 * bsN * sizeof(float) + 6 * bNC * sizeof(u16) +
                2 * pElems * sizeof(float);
  if (ws_size >= need) {
    splits = (u16*)(We + bsN);
    PE = (float*)(splits + 6 * bNC);
    PW = PE + pElems;
  } else {
    // outDe/outDv dead until dedv_fill (after col_reduce) — safe scratch.
    splits = (u16*)outDe;
    PE = outDv;
    PW = PE + pElems;
  }
  u16* Qh = splits;
  u16* Qm = Qh + bNC;
  u16* Ql = Qm + bNC;
  u16* Kh = Ql + bNC;
  u16* Km = Kh + bNC;
  u16* Kl = Km + bNC;

  float rsdh = (float)(1.0 / sqrt((double)C));  // NUM_HEADS==1 -> dh=C
  size_t colsBytes = 2 * (size_t)N * sizeof(float);

  qk_gemm_split<<<dim3(N / 128, 2 * bs), 256, 0, stream>>>(
      Wq, bq, vf, Wk, bk, ef, Qh, Qm, Ql, Kh, Km, Kl, C, N, bs);
  att_mfma<<<dim3(N / 128, N / 128, bs), 256, 0, stream>>>(
      Qh, Qm, Ql, Kh, Km, Kl, H0, outW, C, N, rsdh);
  if (N == 2048)
    topk_select<8><<<dim3(S, bs), 512, colsBytes, stream>>>(
        outW, outH, degV, PE, PW, itp, N);
  else if (N == 1024)
    topk_select<4><<<dim3(S, bs), 512, colsBytes, stream>>>(
        outW, outH, degV, PE, PW, itp, N);
  else  // N == 4096
    topk_select<16><<<dim3(S, bs), 512, colsBytes, stream>>>(
        outW, outH, degV, PE, PW, itp, N);
  col_reduce<<<dim3(N / 256, bs), 256, 0, stream>>>(PE, PW, degE, We, N, S);
  dedv_fill<<<dim3(N / 8, bs, 2), 256, 0, stream>>>(outDe, outDv, degE,
                                                    degV, N);
  wedge_norm<<<dim3(bs), 256, 0, stream>>>(We, outWe, N);
}

// Round 9
// 868.266 us; speedup vs baseline: 1.1305x; 1.1305x over previous
//
#include <hip/hip_runtime.h>
#include <math.h>

#define NUM_LAYER 6

typedef __attribute__((ext_vector_type(8))) short short8;
typedef __attribute__((ext_vector_type(4))) float f32x4;
typedef unsigned short u16;

// Exact 3-way bf16 truncation split: x == h + m + l bit-exactly (8+8+8 bits).
__device__ __forceinline__ void split3(float x, u16& h, u16& m, u16& l) {
  unsigned ux = __float_as_uint(x);
  h = (u16)(ux >> 16);
  float r1 = x - __uint_as_float(ux & 0xFFFF0000u);
  unsigned u1 = __float_as_uint(r1);
  m = (u16)(u1 >> 16);
  float r2 = r1 - __uint_as_float(u1 & 0xFFFF0000u);
  l = (u16)(__float_as_uint(r2) >> 16);
}

// ---------------- Pass A: Q = Wq*vf + bq ; K = Wk*ef + bk ----------------
__global__ __launch_bounds__(256) void qk_gemm_split(
    const float* __restrict__ Wq, const float* __restrict__ bq,
    const float* __restrict__ vf,
    const float* __restrict__ Wk, const float* __restrict__ bk,
    const float* __restrict__ ef,
    u16* __restrict__ Qh, u16* __restrict__ Qm, u16* __restrict__ Ql,
    u16* __restrict__ Kh, u16* __restrict__ Km, u16* __restrict__ Kl,
    int C, int N, int bs) {
  int which = (int)blockIdx.y >= bs;
  int b = (int)blockIdx.y - (which ? bs : 0);
  const float* Wm = which ? Wk : Wq;
  const float* bias = which ? bk : bq;
  const float* X = (which ? ef : vf) + (size_t)b * C * N;
  u16* Ph = which ? Kh : Qh;
  u16* Pm = which ? Km : Qm;
  u16* Pl = which ? Kl : Ql;
  int n0 = blockIdx.x * 128;
  __shared__ float As[8][128];
  __shared__ float Xs[8][128];
  int t = threadIdx.x;
  int tx = t & 15, ty = t >> 4;
  int ao = t >> 1, ac = (t & 1) * 4;
  int lk = t >> 5, lj = (t & 31) * 4;
  float acc[8][8] = {};
  for (int c0 = 0; c0 < C; c0 += 8) {
    __syncthreads();
    float4 wv = *(const float4*)&Wm[(size_t)ao * C + c0 + ac];
    As[ac + 0][ao] = wv.x; As[ac + 1][ao] = wv.y;
    As[ac + 2][ao] = wv.z; As[ac + 3][ao] = wv.w;
    *(float4*)&Xs[lk][lj] = *(const float4*)&X[(size_t)(c0 + lk) * N + n0 + lj];
    __syncthreads();
#pragma unroll
    for (int kk = 0; kk < 8; ++kk) {
      float a[8], bb[8];
      *(float4*)&a[0]  = *(const float4*)&As[kk][ty * 4];
      *(float4*)&a[4]  = *(const float4*)&As[kk][64 + ty * 4];
      *(float4*)&bb[0] = *(const float4*)&Xs[kk][tx * 4];
      *(float4*)&bb[4] = *(const float4*)&Xs[kk][64 + tx * 4];
#pragma unroll
      for (int i = 0; i < 8; ++i)
#pragma unroll
        for (int j = 0; j < 8; ++j)
          acc[i][j] = fmaf(a[i], bb[j], acc[i][j]);
    }
  }
  float bv[8];
#pragma unroll
  for (int i = 0; i < 8; ++i) bv[i] = bias[(i >> 2) * 64 + ty * 4 + (i & 3)];
#pragma unroll
  for (int j = 0; j < 8; ++j) {
    int n = n0 + tx * 4 + (j & 3) + (j >> 2) * 64;
    size_t nb = ((size_t)b * N + n) * C;
#pragma unroll
    for (int g = 0; g < 2; ++g) {
      int r0 = g * 64 + ty * 4;
      ushort4 hv, mv, lv;
      split3(acc[g * 4 + 0][j] + bv[g * 4 + 0], hv.x, mv.x, lv.x);
      split3(acc[g * 4 + 1][j] + bv[g * 4 + 1], hv.y, mv.y, lv.y);
      split3(acc[g * 4 + 2][j] + bv[g * 4 + 2], hv.z, mv.z, lv.z);
      split3(acc[g * 4 + 3][j] + bv[g * 4 + 3], hv.w, mv.w, lv.w);
      *(ushort4*)&Ph[nb + r0] = hv;
      *(ushort4*)&Pm[nb + r0] = mv;
      *(ushort4*)&Pl[nb + r0] = lv;
    }
  }
}

// ---------------- Pass B: score via MFMA bf16 3-split (R7-validated) --------
__global__ __launch_bounds__(256) void att_mfma(
    const u16* __restrict__ Qh, const u16* __restrict__ Qm,
    const u16* __restrict__ Ql, const u16* __restrict__ Kh,
    const u16* __restrict__ Km, const u16* __restrict__ Kl,
    const float* __restrict__ H0, float* __restrict__ score,
    int C, int N, float rsdh) {
  int b = blockIdx.z;
  int o0 = blockIdx.y * 128, i0 = blockIdx.x * 128;
  __shared__ u16 sm[6][128][40];   // [Qh,Qm,Ql,Kh,Km,Kl][row][kpad]
  __shared__ float et[4][16][68];  // per-wave epilogue transpose tile
  int t = threadIdx.x;
  int wave = t >> 6, lane = t & 63, quad = lane >> 4, lr = lane & 15;
  int wo = wave >> 1, wi = wave & 1;
  f32x4 acc[4][4];
#pragma unroll
  for (int mi = 0; mi < 4; ++mi)
#pragma unroll
    for (int ni = 0; ni < 4; ++ni) acc[mi][ni] = (f32x4){0.f, 0.f, 0.f, 0.f};

  int ro = t >> 1, ch = (t & 1) * 16;
  size_t qbase = ((size_t)b * N + o0 + ro) * C + ch;
  size_t kbase = ((size_t)b * N + i0 + ro) * C + ch;
  const u16* gq[3] = {Qh, Qm, Ql};
  const u16* gk[3] = {Kh, Km, Kl};

  for (int c0 = 0; c0 < C; c0 += 32) {
    __syncthreads();
#pragma unroll
    for (int a = 0; a < 3; ++a) {
      const uint4* src = (const uint4*)(gq[a] + qbase + c0);
      *(uint4*)&sm[a][ro][ch] = src[0];
      *(uint4*)&sm[a][ro][ch + 8] = src[1];
      const uint4* srk = (const uint4*)(gk[a] + kbase + c0);
      *(uint4*)&sm[3 + a][ro][ch] = srk[0];
      *(uint4*)&sm[3 + a][ro][ch + 8] = srk[1];
    }
    __syncthreads();
    short8 bh[4], bm[4], bl[4];
#pragma unroll
    for (int ni = 0; ni < 4; ++ni) {
      int row = wi * 64 + ni * 16 + lr;
      bh[ni] = *(const short8*)&sm[3][row][quad * 8];
      bm[ni] = *(const short8*)&sm[4][row][quad * 8];
      bl[ni] = *(const short8*)&sm[5][row][quad * 8];
    }
#pragma unroll
    for (int mi = 0; mi < 4; ++mi) {
      int row = wo * 64 + mi * 16 + lr;
      short8 ah = *(const short8*)&sm[0][row][quad * 8];
      short8 am = *(const short8*)&sm[1][row][quad * 8];
      short8 al = *(const short8*)&sm[2][row][quad * 8];
#pragma unroll
      for (int ni = 0; ni < 4; ++ni) {
        f32x4 c = acc[mi][ni];
        c = __builtin_amdgcn_mfma_f32_16x16x32_bf16(ah, bl[ni], c, 0, 0, 0);
        c = __builtin_amdgcn_mfma_f32_16x16x32_bf16(al, bh[ni], c, 0, 0, 0);
        c = __builtin_amdgcn_mfma_f32_16x16x32_bf16(am, bm[ni], c, 0, 0, 0);
        c = __builtin_amdgcn_mfma_f32_16x16x32_bf16(ah, bm[ni], c, 0, 0, 0);
        c = __builtin_amdgcn_mfma_f32_16x16x32_bf16(am, bh[ni], c, 0, 0, 0);
        c = __builtin_amdgcn_mfma_f32_16x16x32_bf16(ah, bh[ni], c, 0, 0, 0);
        acc[mi][ni] = c;
      }
    }
  }
  const float* Hb = H0 + (size_t)b * N * N;
  float* Sb = score + (size_t)b * N * N;
  int rr = lane >> 2, seg = lane & 3;
#pragma unroll
  for (int mi = 0; mi < 4; ++mi) {
#pragma unroll
    for (int ni = 0; ni < 4; ++ni)
#pragma unroll
      for (int r = 0; r < 4; ++r)
        et[wave][quad * 4 + r][ni * 16 + lr] = acc[mi][ni][r];
    __syncthreads();
    int o = o0 + wo * 64 + mi * 16 + rr;
    const float* hr = Hb + (size_t)o * N + i0 + wi * 64;
    float* sr = Sb + (size_t)o * N + i0 + wi * 64;
#pragma unroll
    for (int j = 0; j < 4; ++j) {
      int col = j * 16 + seg * 4;
      float4 c = *(const float4*)&et[wave][rr][col];
      float4 h = *(const float4*)&hr[col];
      float4 oV;
      oV.x = (h.x > 0.f) ? 1.f / (1.f + __expf(-c.x * rsdh)) : 0.f;
      oV.y = (h.y > 0.f) ? 1.f / (1.f + __expf(-c.y * rsdh)) : 0.f;
      oV.z = (h.z > 0.f) ? 1.f / (1.f + __expf(-c.z * rsdh)) : 0.f;
      oV.w = (h.w > 0.f) ? 1.f / (1.f + __expf(-c.w * rsdh)) : 0.f;
      *(float4*)&sr[col] = oV;
    }
    __syncthreads();  // et reused next mi
  }
}

// ---- Pass C (fused): per-row exact k-th largest + select from registers.
// H0 binary => H = (W>0) ? 1 : 0 (bit-exact); no H0 read needed.
template <int V4>
__global__ __launch_bounds__(512) void topk_select(
    float* __restrict__ scoreW, float* __restrict__ Hout,
    float* __restrict__ degV, float* __restrict__ PE, float* __restrict__ PW,
    const int* __restrict__ itp, int N) {
  int b = blockIdx.y;
  int strip = blockIdx.x;
  int t = threadIdx.x;
  int wave = t >> 6, lane = t & 63;
  int row = strip * 8 + wave;
  size_t rowoff = ((size_t)b * N + row) * N;
  extern __shared__ float cols[];  // [2][N]: colE, colW
  float* colE = cols;
  float* colW = cols + N;
  for (int i = t; i < 2 * N; i += 512) cols[i] = 0.f;

  // phase 1: load row into registers, exact k-th largest (bitwise search)
  float4 v4[V4];
#pragma unroll
  for (int q = 0; q < V4; ++q)
    v4[q] = *(const float4*)(scoreW + rowoff + 4 * lane + (q << 8));
  int itv = *itp;
  int k = (int)floor((double)N * 0.1 * (double)(NUM_LAYER - 1 - itv) + 0.5);
  unsigned lo = 0u, hi = 0x3F800000u;  // scores in [0, 1]
  while (lo < hi) {
    unsigned mid = lo + ((hi - lo + 1u) >> 1);
    float thr = __uint_as_float(mid);
    int c = 0;
#pragma unroll
    for (int q = 0; q < V4; ++q) {
      c += (v4[q].x >= thr) ? 1 : 0;
      c += (v4[q].y >= thr) ? 1 : 0;
      c += (v4[q].z >= thr) ? 1 : 0;
      c += (v4[q].w >= thr) ? 1 : 0;
    }
#pragma unroll
    for (int off = 1; off < 64; off <<= 1) c += __shfl_xor(c, off);
    if (c >= k) lo = mid; else hi = mid - 1u;
  }
  float am = __uint_as_float(lo);  // uniform across wave
  __syncthreads();                 // cols[] zeroed

  // phase 2: select from registers, write W/H, accumulate partials
  float rs = 0.f;
#pragma unroll
  for (int q = 0; q < V4; ++q) {
    int c0 = 4 * lane + (q << 8);
    float4 s = v4[q];
    float4 w, h;
    w.x = (s.x >= am) ? s.x : 0.f; h.x = (w.x > 0.f) ? 1.f : 0.f;
    w.y = (s.y >= am) ? s.y : 0.f; h.y = (w.y > 0.f) ? 1.f : 0.f;
    w.z = (s.z >= am) ? s.z : 0.f; h.z = (w.z > 0.f) ? 1.f : 0.f;
    w.w = (s.w >= am) ? s.w : 0.f; h.w = (w.w > 0.f) ? 1.f : 0.f;
    *(float4*)(scoreW + rowoff + c0) = w;
    *(float4*)(Hout + rowoff + c0) = h;
    rs += h.x + h.y + h.z + h.w;
    if (h.x != 0.f) { atomicAdd(&colE[c0 + 0], 1.f); atomicAdd(&colW[c0 + 0], w.x); }
    if (h.y != 0.f) { atomicAdd(&colE[c0 + 1], 1.f); atomicAdd(&colW[c0 + 1], w.y); }
    if (h.z != 0.f) { atomicAdd(&colE[c0 + 2], 1.f); atomicAdd(&colW[c0 + 2], w.z); }
    if (h.w != 0.f) { atomicAdd(&colE[c0 + 3], 1.f); atomicAdd(&colW[c0 + 3], w.w); }
  }
#pragma unroll
  for (int off = 32; off; off >>= 1) rs += __shfl_down(rs, off);
  if (lane == 0) degV[b * N + row] = rs;
  __syncthreads();
  int S = N >> 3;
  size_t pbase = ((size_t)b * S + strip) * N;
  for (int c = 4 * t; c < N; c += 2048) {
    *(float4*)(PE + pbase + c) = *(const float4*)&colE[c];
    *(float4*)(PW + pbase + c) = *(const float4*)&colW[c];
  }
}

// ---------------- Pass D: reduce column partials -> degE, We ----------------
__global__ __launch_bounds__(256) void col_reduce(
    const float* __restrict__ PE, const float* __restrict__ PW,
    float* __restrict__ degE, float* __restrict__ We, int N, int S) {
  int b = blockIdx.y;
  int col = blockIdx.x * 256 + threadIdx.x;
  float se0 = 0.f, se1 = 0.f, sw0 = 0.f, sw1 = 0.f;
  for (int s = 0; s < S; s += 4) {
    size_t o0 = ((size_t)b * S + s) * N + col;
    se0 += PE[o0];           sw0 += PW[o0];
    se1 += PE[o0 + N];       sw1 += PW[o0 + N];
    se0 += PE[o0 + 2 * (size_t)N]; sw0 += PW[o0 + 2 * (size_t)N];
    se1 += PE[o0 + 3 * (size_t)N]; sw1 += PW[o0 + 3 * (size_t)N];
  }
  degE[b * N + col] = se0 + se1;
  We[b * N + col] = sw0 + sw1;
}

// ------- Pass E: streaming fill of De and Dv (zeros + 1/deg diagonal) -------
__global__ __launch_bounds__(256) void dedv_fill(
    float* __restrict__ De, float* __restrict__ Dv,
    const float* __restrict__ degE, const float* __restrict__ degV, int N) {
  int arr = blockIdx.z;
  int b = blockIdx.y;
  int r0 = blockIdx.x * 8;
  float* out = (arr ? Dv : De) + (size_t)b * N * N;
  const float* deg = (arr ? degV : degE) + b * N;
  int t = threadIdx.x;
#pragma unroll
  for (int r = r0; r < r0 + 8; ++r) {
    float d = deg[r];
    float inv = (d != 0.f) ? 1.f / d : 0.f;
    size_t rowoff = (size_t)r * N;
    for (int c4 = t * 4; c4 < N; c4 += 1024) {
      float4 v = {0.f, 0.f, 0.f, 0.f};
      unsigned dd = (unsigned)(r - c4);
      if (dd < 4u) ((float*)&v)[dd] = inv;
      *(float4*)&out[rowoff + c4] = v;
    }
  }
}

// ---------------- Pass F: W_edge normalize ----------------
__global__ __launch_bounds__(256) void wedge_norm(
    const float* __restrict__ We, float* __restrict__ out, int N) {
  int b = blockIdx.x;
  int t = threadIdx.x;
  const float* w = We + (size_t)b * N;
  float ss = 0.f;
  for (int i = t; i < N; i += 256) { float x = w[i]; ss += x * x; }
  for (int off = 32; off; off >>= 1) ss += __shfl_down(ss, off);
  __shared__ float p[4];
  if ((t & 63) == 0) p[t >> 6] = ss;
  __syncthreads();
  float tot = p[0] + p[1] + p[2] + p[3];
  float nrm = fmaxf(sqrtf(tot), 1e-12f);
  for (int i = t; i < N; i += 256) out[(size_t)b * N + i] = w[i] / nrm;
}

extern "C" void kernel_launch(void* const* d_in, const int* in_sizes, int n_in,
                              void* d_out, int out_size, void* d_ws, size_t ws_size,
                              hipStream_t stream) {
  const float* H0 = (const float*)d_in[0];
  const float* vf = (const float*)d_in[1];
  const float* ef = (const float*)d_in[2];
  const float* Wq = (const float*)d_in[3];
  const float* bq = (const float*)d_in[4];
  const float* Wk = (const float*)d_in[5];
  const float* bk = (const float*)d_in[6];
  const int* itp  = (const int*)d_in[7];

  int C = (int)(sqrt((double)in_sizes[3]) + 0.5);          // 128
  long long ratio = (long long)in_sizes[0] / in_sizes[1];  // N/C
  int N = (int)(C * ratio);                                // 2048
  int bs = (int)(in_sizes[1] / ((long long)C * N));        // 8
  size_t bNN = (size_t)bs * N * N;
  size_t bNC = (size_t)bs * N * C;
  int S = N >> 3;                                          // 8-row strips
  size_t pElems = (size_t)bs * S * N;

  float* outH  = (float*)d_out;
  float* outW  = outH + bNN;
  float* outDe = outW + bNN;
  float* outDv = outDe + bNN;
  float* outWe = outDv + bNN;

  size_t bsN = (size_t)bs * N;
  float* degE = (float*)d_ws;
  float* degV = degE + bsN;
  float* We   = degV + bsN;
  u16* splits;   // 6 arrays of bNC u16 each
  float* PE;
  float* PW;
  size_t need = 3 * bsN * sizeof(float) + 6 * bNC * sizeof(u16) +
                2 * pElems * sizeof(float);
  if (ws_size >= need) {
    splits = (u16*)(We + bsN);
    PE = (float*)(splits + 6 * bNC);
    PW = PE + pElems;
  } else {
    // outDe/outDv dead until dedv_fill (after col_reduce) — safe scratch.
    splits = (u16*)outDe;
    PE = outDv;
    PW = PE + pElems;
  }
  u16* Qh = splits;
  u16* Qm = Qh + bNC;
  u16* Ql = Qm + bNC;
  u16* Kh = Ql + bNC;
  u16* Km = Kh + bNC;
  u16* Kl = Km + bNC;

  float rsdh = (float)(1.0 / sqrt((double)C));  // NUM_HEADS==1 -> dh=C
  size_t colsBytes = 2 * (size_t)N * sizeof(float);

  qk_gemm_split<<<dim3(N / 128, 2 * bs), 256, 0, stream>>>(
      Wq, bq, vf, Wk, bk, ef, Qh, Qm, Ql, Kh, Km, Kl, C, N, bs);
  att_mfma<<<dim3(N / 128, N / 128, bs), 256, 0, stream>>>(
      Qh, Qm, Ql, Kh, Km, Kl, H0, outW, C, N, rsdh);
  if (N == 2048)
    topk_select<8><<<dim3(S, bs), 512, colsBytes, stream>>>(
        outW, outH, degV, PE, PW, itp, N);
  else if (N == 1024)
    topk_select<4><<<dim3(S, bs), 512, colsBytes, stream>>>(
        outW, outH, degV, PE, PW, itp, N);
  else  // N == 4096
    topk_select<16><<<dim3(S, bs), 512, colsBytes, stream>>>(
        outW, outH, degV, PE, PW, itp, N);
  col_reduce<<<dim3(N / 256, bs), 256, 0, stream>>>(PE, PW, degE, We, N, S);
  dedv_fill<<<dim3(N / 8, bs, 2), 256, 0, stream>>>(outDe, outDv, degE,
                                                    degV, N);
  wedge_norm<<<dim3(bs), 256, 0, stream>>>(We, outWe, N);
}